// Round 11
// baseline (265.373 us; speedup 1.0000x reference)
//
#include <hip/hip_runtime.h>
#include <math.h>

// Top-1 MoE, 6-dispatch pipeline.
//   memset -> prep -> gate_partial -> gate_finalize -> gemm1+coefgemm -> gemm2.
// r14: XCD-chunked swizzle. r15: gate 128x128 + global_load_lds.
// r19: depth-3 counted-vmcnt pipeline on gemm1/gemm2 (both left top-5).
// r20: cheap experts = rank-27 linear map -> dense MFMA coefficient-GEMM
// (replaced the 50us gather-bound cheap kernel; 283->260).
// r21: gate_partial gets the same r19 treatment: (a) drop the lo x lo partial
// (c2=3; bounded by ~2.6e-6 on a logit -- noise), 25% less gate work and
// hp 32->24MB; (b) BK=32 depth-3 counted-vmcnt pipeline, 48KB LDS, 5 vm-ops
// per tile (4 glds16 + 1 cheap-frag load in 3 rotating registers), waits
// vmcnt(10/5/0) + raw s_barrier -- no drain in the main loop.
// (r21 resubmission: previous round hit GPUAcquisitionTimeout, no data.)

#define E 1024
#define GH 256
#define NEXP 6
#define NTOK 8192
#define NCH 24   // cheap-dot cols: 2 p2 + 4 p4 + 1 rg + 16 film + 1 pad

typedef __attribute__((ext_vector_type(8))) short bf16x8;
typedef __attribute__((ext_vector_type(4))) float f32x4;

__device__ __forceinline__ float gelu_erf(float v) {
    return 0.5f * v * (1.0f + erff(v * 0.70710678118654752440f));
}

__device__ __forceinline__ unsigned short f2bf(float f) {
    union { float f; unsigned u; } c; c.f = f;
    unsigned u = c.u;
    u += 0x7fffu + ((u >> 16) & 1u);   // RNE
    return (unsigned short)(u >> 16);
}

__device__ __forceinline__ float bf2f(unsigned short h) {
    union { unsigned u; float f; } c; c.u = ((unsigned)h) << 16;
    return c.f;
}

// LDS tile addressing (ushort units) within a [rows][32] sub-tile:
// row stride 32 (=64B), k-group XOR swizzle.
__device__ __forceinline__ int ldso(int row, int q) {
    return row * 32 + ((q ^ ((row >> 1) & 3)) << 3);
}

// async global->LDS, 16B per lane; lds dest is wave-uniform base + lane*16.
__device__ __forceinline__ void glds16(const void* g, void* l) {
    __builtin_amdgcn_global_load_lds(
        (const __attribute__((address_space(1))) void*)g,
        (__attribute__((address_space(3))) void*)l, 16, 0, 0);
}

// ---------------- prep: convert + all transposes, one kernel ----------------
__global__ __launch_bounds__(256)
void prep_kernel(const float* __restrict__ x, unsigned short* __restrict__ xh,
                 unsigned short* __restrict__ xl,
                 const float* __restrict__ gw1, unsigned short* __restrict__ w1cat,
                 const float* __restrict__ p2_w, const float* __restrict__ p4_w,
                 const float* __restrict__ rg_u, const float* __restrict__ fl_dw,
                 unsigned short* __restrict__ w1cheap,
                 const float* __restrict__ p2_bias, const float* __restrict__ p2_v,
                 const float* __restrict__ p4_bias, const float* __restrict__ p4_v,
                 const float* __restrict__ rg_a, const float* __restrict__ rg_bias,
                 const float* __restrict__ fl_uw, const float* __restrict__ fl_ub,
                 unsigned short* __restrict__ bta, unsigned short* __restrict__ btm,
                 const float* __restrict__ dfc_w, unsigned short* __restrict__ dfc_wt,
                 const float* __restrict__ dproj_w, unsigned short* __restrict__ dpj_wt,
                 const float* __restrict__ sfc_w, unsigned short* __restrict__ sfc_wt,
                 const float* __restrict__ sproj_w, unsigned short* __restrict__ spj_wt) {
    __shared__ float tile[32][33];
    const int tid = threadIdx.x;
    const int tx = tid & 31, ty = tid >> 5;
    int b = blockIdx.x;
    if (b < 2048) {                       // x -> x_hi + x_lo
        const int n4 = NTOK * E / 4;
        for (int i = b * 256 + tid; i < n4; i += 2048 * 256) {
            float4 v = reinterpret_cast<const float4*>(x)[i];
            ushort4 h, l;
            h.x = f2bf(v.x); l.x = f2bf(v.x - bf2f(h.x));
            h.y = f2bf(v.y); l.y = f2bf(v.y - bf2f(h.y));
            h.z = f2bf(v.z); l.z = f2bf(v.z - bf2f(h.z));
            h.w = f2bf(v.w); l.w = f2bf(v.w - bf2f(h.w));
            reinterpret_cast<ushort4*>(xh)[i] = h;
            reinterpret_cast<ushort4*>(xl)[i] = l;
        }
        return;
    }
    b -= 2048;
    if (b < 256) {                        // gw1 [E][GH] -> w1cat [GH][hi|lo]
        const int c0 = (b & 7) * 32, r0 = (b >> 3) * 32;
#pragma unroll
        for (int i = 0; i < 4; ++i)
            tile[ty + i * 8][tx] = gw1[(size_t)(r0 + ty + i * 8) * GH + c0 + tx];
        __syncthreads();
#pragma unroll
        for (int i = 0; i < 4; ++i) {
            float v = tile[tx][ty + i * 8];
            unsigned short h = f2bf(v);
            size_t row = (size_t)(c0 + ty + i * 8) * 2048;
            w1cat[row + r0 + tx] = h;
            w1cat[row + 1024 + r0 + tx] = f2bf(v - bf2f(h));
        }
        return;
    }
    b -= 256;
    if (b < 64) {                         // cheap-dot weights -> w1cheap [64][hi|lo]
        const int r = b;
        const int k4 = tid * 4;
        float4 v = {0.f, 0.f, 0.f, 0.f};
        if (r < 2)       v = *reinterpret_cast<const float4*>(&p2_w[r * E + k4]);
        else if (r < 6)  v = *reinterpret_cast<const float4*>(&p4_w[(r - 2) * E + k4]);
        else if (r == 6) v = *reinterpret_cast<const float4*>(&rg_u[k4]);
        else if (r < 23) {
            const int j = r - 7;          // fl_dw is [E][16]: gather column j
            v.x = fl_dw[(k4 + 0) * 16 + j];
            v.y = fl_dw[(k4 + 1) * 16 + j];
            v.z = fl_dw[(k4 + 2) * 16 + j];
            v.w = fl_dw[(k4 + 3) * 16 + j];
        }
        ushort4 h, l;
        h.x = f2bf(v.x); l.x = f2bf(v.x - bf2f(h.x));
        h.y = f2bf(v.y); l.y = f2bf(v.y - bf2f(h.y));
        h.z = f2bf(v.z); l.z = f2bf(v.z - bf2f(h.z));
        h.w = f2bf(v.w); l.w = f2bf(v.w - bf2f(h.w));
        *reinterpret_cast<ushort4*>(&w1cheap[r * 2048 + k4]) = h;
        *reinterpret_cast<ushort4*>(&w1cheap[r * 2048 + 1024 + k4]) = l;
        return;
    }
    b -= 64;
    if (b < 4) {                          // cheap basis: Bt_add/Bt_mul [1024][64]
        const int n = b * 256 + tid;      // output column in [0, E)
        float av[32], mv[32];
#pragma unroll
        for (int r = 0; r < 32; ++r) { av[r] = 0.f; mv[r] = 0.f; }
        av[0] = p2_bias[n];
        av[1] = p2_v[n]; av[2] = p2_v[E + n];
        av[3] = p4_bias[n];
#pragma unroll
        for (int j = 0; j < 4; ++j) av[4 + j] = p4_v[j * E + n];
        av[8] = rg_bias[n];
        mv[9] = rg_a[n];
        av[10] = fl_ub[E + n];            // beta const
        mv[10] = fl_ub[n];                // gamma const
#pragma unroll
        for (int j = 0; j < 16; ++j) {
            av[11 + j] = fl_uw[(size_t)j * 2 * E + E + n];   // beta weights
            mv[11 + j] = fl_uw[(size_t)j * 2 * E + n];       // gamma weights
        }
#pragma unroll
        for (int r = 0; r < 32; ++r) {
            unsigned short ha = f2bf(av[r]), hm = f2bf(mv[r]);
            bta[n * 64 + r] = ha; bta[n * 64 + 32 + r] = ha;  // dup for lo-coeff half
            btm[n * 64 + r] = hm; btm[n * 64 + 32 + r] = hm;
        }
        return;
    }
    b -= 4;
    const float* src; unsigned short* dst; int R, C, nbx;
    if (b < 2048)      { src = dfc_w;   dst = dfc_wt; R = 1024; C = 2048; nbx = 64; }
    else if (b < 4096) { src = dproj_w; dst = dpj_wt; R = 2048; C = 1024; nbx = 32; b -= 2048; }
    else if (b < 5120) { src = sfc_w;   dst = sfc_wt; R = 1024; C = 1024; nbx = 32; b -= 4096; }
    else               { src = sproj_w; dst = spj_wt; R = 1024; C = 1024; nbx = 32; b -= 5120; }
    const int c0 = (b % nbx) * 32, r0 = (b / nbx) * 32;
#pragma unroll
    for (int i = 0; i < 4; ++i)
        tile[ty + i * 8][tx] = src[(size_t)(r0 + ty + i * 8) * C + c0 + tx];
    __syncthreads();
#pragma unroll
    for (int i = 0; i < 4; ++i)
        dst[(size_t)(c0 + ty + i * 8) * R + r0 + tx] = f2bf(tile[tx][ty + i * 8]);
}

// ------ gate partial GEMM: hp[c2] = A_z @ w1cat[:, h-half], 128x128 tiles ---
// Grid 384 (lo x lo partial dropped: c2 in {0,1,2}). Decode: xcd=bid&7,
// slot=bid>>3 in [0,48); nx=slot&1; idx=xcd*24+(slot>>1); m=idx/3, c2=idx%3
// (z=c2&1, h=c2>>1). The 6 blocks of one m-group share an XCD's L2.
// BK=32, depth-3 counted-vmcnt pipeline: 3 LDS buffers (48KB), 5 vm-ops per
// tile (4 glds16 + 1 cheap fragment in 3 rotating regs), vmcnt(10/5/0) + raw
// s_barrier -- no drain in the main loop. Cheap dots: +2 MFMAs per tile.
__global__ __launch_bounds__(256)
void gate_partial_kernel(const unsigned short* __restrict__ xh,
                         const unsigned short* __restrict__ xl,
                         const unsigned short* __restrict__ w1cat,
                         const unsigned short* __restrict__ w1cheap,
                         float* __restrict__ hp,      // [3][NTOK][GH]
                         float* __restrict__ cdot) {  // [3][NTOK][NCH]
    __shared__ __align__(16) unsigned short As[3][128 * 32];   // 24 KB
    __shared__ __align__(16) unsigned short Bs[3][128 * 32];   // 24 KB
    const int tid = threadIdx.x;
    const int bid = blockIdx.x;
    const int xcd = bid & 7, slot = bid >> 3;      // [0,48)
    const int nx = slot & 1;
    const int idx = xcd * 24 + (slot >> 1);        // [0,192)
    const int m = idx / 3, c2 = idx - 3 * m;       // m in [0,64), c2 in {0,1,2}
    const int z = c2 & 1, h = c2 >> 1;
    const int t0 = m * 128, n0 = nx * 128;
    const unsigned short* A = z ? xl : xh;
    float* hpz = hp + (size_t)c2 * ((size_t)NTOK * GH);
    float* cd  = cdot + (size_t)c2 * ((size_t)NTOK * NCH);

    const int lane = tid & 63, wv = tid >> 6;
    const int wr = wv >> 1, wc = wv & 1;
    const int lm = lane & 15, q = lane >> 4;
    const int r0 = tid >> 2, gsl = tid & 3;
    const int g = gsl ^ ((r0 >> 1) & 3);
    const int lbase = wv * 512;

    const unsigned short* pa0 = A + (size_t)(t0 + r0) * E + g * 8;
    const unsigned short* pa1 = A + (size_t)(t0 + 64 + r0) * E + g * 8;
    const unsigned short* pb0 = w1cat + (size_t)(n0 + r0) * 2048 + h * 1024 + g * 8;
    const unsigned short* pb1 = w1cat + (size_t)(n0 + 64 + r0) * 2048 + h * 1024 + g * 8;
    const unsigned short* pcw = w1cheap + (size_t)(nx * 16 + lm) * 2048 + h * 1024 + q * 8;

    f32x4 acc[4][4];
#pragma unroll
    for (int s = 0; s < 4; ++s)
#pragma unroll
        for (int t = 0; t < 4; ++t) acc[s][t] = (f32x4){0.f, 0.f, 0.f, 0.f};
    f32x4 accC[2];
    accC[0] = (f32x4){0.f, 0.f, 0.f, 0.f};
    accC[1] = (f32x4){0.f, 0.f, 0.f, 0.f};

#define GSTAGE(t, jb)                                            \
    do {                                                         \
        glds16(pa0 + (t) * 32, &As[jb][lbase]);                  \
        glds16(pa1 + (t) * 32, &As[jb][2048 + lbase]);           \
        glds16(pb0 + (t) * 32, &Bs[jb][lbase]);                  \
        glds16(pb1 + (t) * 32, &Bs[jb][2048 + lbase]);           \
    } while (0)

    GSTAGE(0, 0); bf16x8 cfA = *(const bf16x8*)(pcw);
    GSTAGE(1, 1); bf16x8 cfB = *(const bf16x8*)(pcw + 32);
    GSTAGE(2, 2); bf16x8 cfC = *(const bf16x8*)(pcw + 64);

    const int nt = 32;                    // K = 1024, BK = 32
    for (int i = 0; i < nt; ++i) {
        const int ahead = nt - 1 - i;
        if (ahead >= 2)      asm volatile("s_waitcnt vmcnt(10)" ::: "memory");
        else if (ahead == 1) asm volatile("s_waitcnt vmcnt(5)" ::: "memory");
        else                 asm volatile("s_waitcnt vmcnt(0)" ::: "memory");
        asm volatile("s_barrier" ::: "memory");   // tile i landed (LDS + cfA)
        const int jb = i % 3;
        bf16x8 af[4], bfr[4];
#pragma unroll
        for (int s = 0; s < 4; ++s) af[s] = *(const bf16x8*)&As[jb][ldso(wr * 64 + s * 16 + lm, q)];
#pragma unroll
        for (int t = 0; t < 4; ++t) bfr[t] = *(const bf16x8*)&Bs[jb][ldso(wc * 64 + t * 16 + lm, q)];
#pragma unroll
        for (int s = 0; s < 4; ++s)
#pragma unroll
            for (int t = 0; t < 4; ++t)
                acc[s][t] = __builtin_amdgcn_mfma_f32_16x16x32_bf16(af[s], bfr[t], acc[s][t], 0, 0, 0);
        {
            bf16x8 ac0 = wc ? af[2] : af[0];
            bf16x8 ac1 = wc ? af[3] : af[1];
            accC[0] = __builtin_amdgcn_mfma_f32_16x16x32_bf16(ac0, cfA, accC[0], 0, 0, 0);
            accC[1] = __builtin_amdgcn_mfma_f32_16x16x32_bf16(ac1, cfA, accC[1], 0, 0, 0);
        }
        asm volatile("s_barrier" ::: "memory");   // all waves done with buf jb
        bf16x8 cfn = cfA;
        if (i + 3 < nt) {
            GSTAGE(i + 3, jb);
            cfn = *(const bf16x8*)(pcw + (i + 3) * 32);
        }
        cfA = cfB; cfB = cfC; cfC = cfn;
    }
#undef GSTAGE
#pragma unroll
    for (int s = 0; s < 4; ++s)
#pragma unroll
        for (int t = 0; t < 4; ++t)
#pragma unroll
            for (int rg = 0; rg < 4; ++rg) {
                int rl = wr * 64 + s * 16 + q * 4 + rg;
                int c  = wc * 64 + t * 16 + lm;
                hpz[(size_t)(t0 + rl) * GH + n0 + c] = acc[s][t][rg];
            }
    const int cc = nx * 16 + lm;
    if (cc < NCH) {
#pragma unroll
        for (int i = 0; i < 2; ++i)
#pragma unroll
            for (int rg = 0; rg < 4; ++rg) {
                int rl = wr * 64 + wc * 32 + i * 16 + q * 4 + rg;
                cd[(size_t)(t0 + rl) * NCH + cc] = accC[i][rg];
            }
    }
}

// ------- finalize: h=gelu(sum3 hp+gb1); logits=h@gw2; softmax/argmax --------
// Emits per-token coefficient rows Cm[8192][64] bf16 (hi|lo) for the
// cheap coefficient-GEMM; zero rows for experts 0/1.
__global__ __launch_bounds__(256)
void gate_finalize_kernel(const float* __restrict__ hp,    // [3][NTOK][GH]
                          const float* __restrict__ gb1, const float* __restrict__ gw2,
                          const float* __restrict__ gb2, const float* __restrict__ ebias,
                          const float* __restrict__ pm_alpha,
                          const float* __restrict__ cdot,  // [3][NTOK][NCH]
                          const float* __restrict__ p2_alpha, const float* __restrict__ p2_b,
                          const float* __restrict__ p4_alpha, const float* __restrict__ p4_b,
                          const float* __restrict__ rg_b, const float* __restrict__ fl_db,
                          float* __restrict__ scale, int* __restrict__ counts,
                          int* __restrict__ tlist,
                          unsigned short* __restrict__ Cm) {
    __shared__ float hs[32][264];
    __shared__ float g2s[GH * NEXP];
    __shared__ int tokexp[32];
    const int tid = threadIdx.x;
    const int t0 = blockIdx.x * 32;
    const size_t HPS = (size_t)NTOK * GH;
    for (int i = tid; i < GH * NEXP; i += 256) g2s[i] = gw2[i];
#pragma unroll
    for (int i = 0; i < 8; ++i) {
        int f4 = i * 256 + tid;
        int row = f4 >> 6, c4 = (f4 & 63) * 4;
        size_t base = (size_t)(t0 + row) * GH + c4;
        float4 a = *reinterpret_cast<const float4*>(&hp[base]);
        float4 b = *reinterpret_cast<const float4*>(&hp[HPS + base]);
        float4 c = *reinterpret_cast<const float4*>(&hp[2 * HPS + base]);
        float4 o;
        o.x = gelu_erf(a.x + b.x + c.x + gb1[c4 + 0]);
        o.y = gelu_erf(a.y + b.y + c.y + gb1[c4 + 1]);
        o.z = gelu_erf(a.z + b.z + c.z + gb1[c4 + 2]);
        o.w = gelu_erf(a.w + b.w + c.w + gb1[c4 + 3]);
        *reinterpret_cast<float4*>(&hs[row][c4]) = o;
    }
    __syncthreads();
    const int t = tid >> 3, j = tid & 7;
    float p[NEXP] = {0.f, 0.f, 0.f, 0.f, 0.f, 0.f};
#pragma unroll 8
    for (int kk = 0; kk < 32; ++kk) {
        int k = j + kk * 8;
        float hv = hs[t][k];
        const float* gr = &g2s[k * NEXP];
#pragma unroll
        for (int m = 0; m < NEXP; ++m) p[m] += hv * gr[m];
    }
#pragma unroll
    for (int m = 0; m < NEXP; ++m) {
        p[m] += __shfl_xor(p[m], 4, 64);
        p[m] += __shfl_xor(p[m], 2, 64);
        p[m] += __shfl_xor(p[m], 1, 64);
    }
    if (j == 0) {
        float L[NEXP];
#pragma unroll
        for (int m = 0; m < NEXP; ++m) L[m] = p[m] + gb2[m] + ebias[m];
        float mx = L[0]; int am = 0;
#pragma unroll
        for (int m = 1; m < NEXP; ++m) { if (L[m] > mx) { mx = L[m]; am = m; } }
        float S = 0.f;
#pragma unroll
        for (int m = 0; m < NEXP; ++m) S += expf(L[m] - mx);
        float pt = 1.f / S;
        scale[t0 + t] = pm_alpha[0] * (pt / (pt + 1e-9f));
        tokexp[t] = am;
    }
    __syncthreads();
    if (tid < NEXP) {
        const int e = tid;
        int cnt = 0;
#pragma unroll
        for (int i = 0; i < 32; ++i) cnt += (tokexp[i] == e);
        if (cnt) {
            int base = atomicAdd(&counts[e], cnt);
            int pos = 0;
#pragma unroll
            for (int i = 0; i < 32; ++i)
                if (tokexp[i] == e) tlist[e * NTOK + base + (pos++)] = t0 + i;
        }
    }
    // ---- per-token coefficient rows for the cheap coefficient-GEMM ----
    const size_t CDS = (size_t)NTOK * NCH;
    for (int i = tid; i < 32 * 32; i += 256) {
        const int tt = i >> 5, r = i & 31;
        const int tok = t0 + tt;
        const int e = tokexp[tt];
        float c = 0.f;
        int slot = -1;
        if (r == 0)       { if (e == 2) c = 1.f; }
        else if (r <= 2)  { if (e == 2) slot = r - 1; }
        else if (r == 3)  { if (e == 3) c = 1.f; }
        else if (r <= 7)  { if (e == 3) slot = r - 2; }
        else if (r == 8)  { if (e == 4) c = 1.f; }
        else if (r == 9)  { if (e == 4) slot = 6; }
        else if (r == 10) { if (e == 5) c = 1.f; }
        else if (r <= 26) { if (e == 5) slot = r - 4; }
        if (slot >= 0) {
            size_t idx = (size_t)tok * NCH + slot;
            float s = cdot[idx] + cdot[CDS + idx] + cdot[2 * CDS + idx];
            if (slot < 2)       c = p2_alpha[slot] * gelu_erf(s + p2_b[slot]);
            else if (slot < 6)  c = p4_alpha[slot - 2] * gelu_erf(s + p4_b[slot - 2]);
            else if (slot == 6) c = 1.f / (1.f + expf(-(s + rg_b[0])));
            else                c = gelu_erf(s + fl_db[slot - 7]);
        }
        unsigned short hi = f2bf(c);
        Cm[(size_t)tok * 64 + r] = hi;
        Cm[(size_t)tok * 64 + 32 + r] = f2bf(c - bf2f(hi));
    }
}

// ---- depth-3 counted-vmcnt pipelined staging: 4 glds16 per tile per thread.
#define STAGEAB(t, jb)                                            \
    do {                                                          \
        glds16(pa + (t) * 64,      &As[jb][lbase]);               \
        glds16(pa + (t) * 64 + 32, &As[jb][2048 + lbase]);        \
        glds16(pb + (t) * 64,      &Bs[jb][lbase]);               \
        glds16(pb + (t) * 64 + 32, &Bs[jb][2048 + lbase]);        \
    } while (0)

// -------- GEMM1 (gather x_hi -> gelu -> bf16 h) + cheap coefficient-GEMM ----
// blocks [0,2048): gemm1, 64x64 tiles, depth-3 counted-vmcnt pipeline.
// blocks [2048,4096): coefgemm: out[8192][1024] = (Cm@Btm . x + Cm@Bta)*scale,
// dense over ALL tokens (e0/e1 rows get zeros; gemm2 overwrites them next
// dispatch). M=8192 (128 mtiles), N=1024 (16 ntiles), K=64, single K-tile.
__global__ __launch_bounds__(256)
void moe_gemm1_kernel(const unsigned short* __restrict__ xh,
                      const unsigned short* __restrict__ B0, const unsigned short* __restrict__ B1,
                      const float* __restrict__ bias0, const float* __restrict__ bias1,
                      const int* __restrict__ counts, const int* __restrict__ tlist,
                      unsigned short* __restrict__ H0, unsigned short* __restrict__ H1,
                      const unsigned short* __restrict__ Cm,
                      const unsigned short* __restrict__ bta, const unsigned short* __restrict__ btm,
                      const float* __restrict__ x, const float* __restrict__ scale,
                      float* __restrict__ out) {
    __shared__ __align__(16) unsigned short As[3][64 * 64];   // 24 KB
    __shared__ __align__(16) unsigned short Bs[3][64 * 64];   // 24 KB
    __shared__ int toks[64];
    const int tid = threadIdx.x;
    const int bid = blockIdx.x;
    const int lane = tid & 63, wv = tid >> 6;
    const int wm = (wv & 1) * 32, wn = (wv >> 1) * 32;
    const int lm = lane & 15, q = lane >> 4;
    const int r0 = tid >> 2, gsl = tid & 3;
    const int g = gsl ^ ((r0 >> 1) & 3);
    const int lbase = wv * 512;

    if (bid >= 2048) {
        // ---- cheap coefficient-GEMM ----
        const int cg = bid - 2048;
        const int xcd = cg & 7, s = cg >> 3;       // [0,256)
        const int nx = s & 15;
        const int mt = xcd + 8 * (s >> 4);         // [0,128)
        const int t0 = mt * 64, n0 = nx * 64;
        unsigned short* Ct = &As[0][0];
        unsigned short* Ba = &As[1][0];
        unsigned short* Bm = &As[2][0];

        const unsigned short* pc = Cm + (size_t)(t0 + r0) * 64 + g * 8;
        const unsigned short* pba = bta + (size_t)(n0 + r0) * 64 + g * 8;
        const unsigned short* pbm = btm + (size_t)(n0 + r0) * 64 + g * 8;
        glds16(pc,       &Ct[lbase]);
        glds16(pc + 32,  &Ct[2048 + lbase]);
        glds16(pba,      &Ba[lbase]);
        glds16(pba + 32, &Ba[2048 + lbase]);
        glds16(pbm,      &Bm[lbase]);
        glds16(pbm + 32, &Bm[2048 + lbase]);

        f32x4 accA[2][2], accM[2][2];
#pragma unroll
        for (int s2 = 0; s2 < 2; ++s2)
#pragma unroll
            for (int t2 = 0; t2 < 2; ++t2) {
                accA[s2][t2] = (f32x4){0.f, 0.f, 0.f, 0.f};
                accM[s2][t2] = (f32x4){0.f, 0.f, 0.f, 0.f};
            }
        __syncthreads();                           // drains vmcnt
#pragma unroll
        for (int sub = 0; sub < 2; ++sub) {
            const int off = sub * 2048;
            bf16x8 af[2], ba[2], bm[2];
#pragma unroll
            for (int s2 = 0; s2 < 2; ++s2) af[s2] = *(const bf16x8*)&Ct[off + ldso(wm + s2 * 16 + lm, q)];
#pragma unroll
            for (int t2 = 0; t2 < 2; ++t2) {
                ba[t2] = *(const bf16x8*)&Ba[off + ldso(wn + t2 * 16 + lm, q)];
                bm[t2] = *(const bf16x8*)&Bm[off + ldso(wn + t2 * 16 + lm, q)];
            }
#pragma unroll
            for (int s2 = 0; s2 < 2; ++s2)
#pragma unroll
                for (int t2 = 0; t2 < 2; ++t2) {
                    accA[s2][t2] = __builtin_amdgcn_mfma_f32_16x16x32_bf16(af[s2], ba[t2], accA[s2][t2], 0, 0, 0);
                    accM[s2][t2] = __builtin_amdgcn_mfma_f32_16x16x32_bf16(af[s2], bm[t2], accM[s2][t2], 0, 0, 0);
                }
        }
#pragma unroll
        for (int s2 = 0; s2 < 2; ++s2)
#pragma unroll
            for (int t2 = 0; t2 < 2; ++t2)
#pragma unroll
                for (int rg = 0; rg < 4; ++rg) {
                    int rl = wm + s2 * 16 + q * 4 + rg;
                    int gc = n0 + wn + t2 * 16 + lm;
                    int tok = t0 + rl;
                    float xv = x[(size_t)tok * E + gc];
                    out[(size_t)tok * E + gc] =
                        scale[tok] * (accM[s2][t2][rg] * xv + accA[s2][t2][rg]);
                }
        return;
    }

    // ---- gemm1 ----
    const int xcd = bid & 7, slot = bid >> 3;      // [0,256)
    const int nx = slot & 31;
    const int strip = xcd + 8 * (slot >> 5);       // [0,64), XCD-strided
    const int z = strip & 1;
    const int N = z ? 1024 : 2048;
    const int cnt = counts[z];
    const int i0 = (strip >> 1) * 64;
    const int n0 = nx * 64;
    if (i0 >= cnt || n0 >= N) return;
    const unsigned short* Bz = z ? B1 : B0;
    const float* bias = z ? bias1 : bias0;

    if (tid < 64) toks[tid] = tlist[z * NTOK + min(i0 + tid, cnt - 1)];
    __syncthreads();

    const unsigned short* pa = xh + (size_t)toks[r0] * E + g * 8;
    const unsigned short* pb = Bz + (size_t)(n0 + r0) * E + g * 8;

    f32x4 acc[2][2];
#pragma unroll
    for (int s = 0; s < 2; ++s)
#pragma unroll
        for (int t = 0; t < 2; ++t) acc[s][t] = (f32x4){0.f, 0.f, 0.f, 0.f};

    STAGEAB(0, 0); STAGEAB(1, 1); STAGEAB(2, 2);

    const int nt = E / 64;                        // 16
    for (int i = 0; i < nt; ++i) {
        const int ahead = nt - 1 - i;
        if (ahead >= 2)      asm volatile("s_waitcnt vmcnt(8)" ::: "memory");
        else if (ahead == 1) asm volatile("s_waitcnt vmcnt(4)" ::: "memory");
        else                 asm volatile("s_waitcnt vmcnt(0)" ::: "memory");
        asm volatile("s_barrier" ::: "memory");   // all waves: tile i landed
        const int jb = i % 3;
#pragma unroll
        for (int sub = 0; sub < 2; ++sub) {
            const int off = sub * 2048;
            bf16x8 af[2], bfr[2];
#pragma unroll
            for (int s = 0; s < 2; ++s) af[s] = *(const bf16x8*)&As[jb][off + ldso(wm + s * 16 + lm, q)];
#pragma unroll
            for (int t = 0; t < 2; ++t) bfr[t] = *(const bf16x8*)&Bs[jb][off + ldso(wn + t * 16 + lm, q)];
#pragma unroll
            for (int s = 0; s < 2; ++s)
#pragma unroll
                for (int t = 0; t < 2; ++t)
                    acc[s][t] = __builtin_amdgcn_mfma_f32_16x16x32_bf16(af[s], bfr[t], acc[s][t], 0, 0, 0);
        }
        asm volatile("s_barrier" ::: "memory");   // all waves done reading buf
        if (i + 3 < nt) STAGEAB(i + 3, jb);
    }
    unsigned short* Hz = z ? H1 : H0;
#pragma unroll
    for (int s = 0; s < 2; ++s)
#pragma unroll
        for (int t = 0; t < 2; ++t)
#pragma unroll
            for (int rg = 0; rg < 4; ++rg) {
                int rl = wm + s * 16 + q * 4 + rg;
                int gc = n0 + wn + t * 16 + lm;
                float v = acc[s][t][rg] + bias[gc];
                Hz[(size_t)(i0 + rl) * N + gc] = f2bf(gelu_erf(v));
            }
}

// ---------------- GEMM2 (experts 0/1 down-proj), pure GEMM ------------------
// Grid 1024. 64x64 tiles, BK=64, depth-3 counted-vmcnt pipeline (48KB LDS).
__global__ __launch_bounds__(256)
void moe_gemm2_kernel(const unsigned short* __restrict__ h1, const unsigned short* __restrict__ h2,
                      const unsigned short* __restrict__ dpj, const unsigned short* __restrict__ spj,
                      const float* __restrict__ dproj_b, const float* __restrict__ sproj_b,
                      const int* __restrict__ counts, const int* __restrict__ tlist,
                      const float* __restrict__ scale,
                      float* __restrict__ out) {
    __shared__ __align__(16) unsigned short As[3][64 * 64];   // 24 KB
    __shared__ __align__(16) unsigned short Bs[3][64 * 64];   // 24 KB
    __shared__ int toks[64];
    const int tid = threadIdx.x;
    const int bb = blockIdx.x;
    const int lane = tid & 63;

    const int xcd = bb & 7, slot = bb >> 3;    // [0,128)
    const int nx = slot & 15;
    const int strip = xcd + 8 * (slot >> 4);   // [0,64)
    const int z = strip & 1;
    const int i0 = (strip >> 1) * 64;
    const int n0 = nx * 64;
    const int K = z ? 1024 : 2048;
    const int cnt = counts[z];
    if (i0 >= cnt) return;
    const int rows = min(64, cnt - i0);
    const unsigned short* Az = z ? h2 : h1;
    const unsigned short* Bz = z ? spj : dpj;
    const float* bias = z ? sproj_b : dproj_b;

    if (tid < 64) toks[tid] = tlist[z * NTOK + min(i0 + tid, cnt - 1)];
    __syncthreads();

    const int wv = tid >> 6;
    const int wm = (wv & 1) * 32, wn = (wv >> 1) * 32;
    const int lm = lane & 15, q = lane >> 4;
    const int r0 = tid >> 2, gsl = tid & 3;
    const int g = gsl ^ ((r0 >> 1) & 3);
    const int lbase = wv * 512;

    const unsigned short* pa = Az + (size_t)(i0 + r0) * K + g * 8;
    const unsigned short* pb = Bz + (size_t)(n0 + r0) * K + g * 8;

    f32x4 acc[2][2];
#pragma unroll
    for (int s = 0; s < 2; ++s)
#pragma unroll
        for (int t = 0; t < 2; ++t) acc[s][t] = (f32x4){0.f, 0.f, 0.f, 0.f};

    STAGEAB(0, 0); STAGEAB(1, 1); STAGEAB(2, 2);

    const int nt = K / 64;                        // 16 or 32
    for (int i = 0; i < nt; ++i) {
        const int ahead = nt - 1 - i;
        if (ahead >= 2)      asm volatile("s_waitcnt vmcnt(8)" ::: "memory");
        else if (ahead == 1) asm volatile("s_waitcnt vmcnt(4)" ::: "memory");
        else                 asm volatile("s_waitcnt vmcnt(0)" ::: "memory");
        asm volatile("s_barrier" ::: "memory");
        const int jb = i % 3;
#pragma unroll
        for (int sub = 0; sub < 2; ++sub) {
            const int off = sub * 2048;
            bf16x8 af[2], bfr[2];
#pragma unroll
            for (int s = 0; s < 2; ++s) af[s] = *(const bf16x8*)&As[jb][off + ldso(wm + s * 16 + lm, q)];
#pragma unroll
            for (int t = 0; t < 2; ++t) bfr[t] = *(const bf16x8*)&Bs[jb][off + ldso(wn + t * 16 + lm, q)];
#pragma unroll
            for (int s = 0; s < 2; ++s)
#pragma unroll
                for (int t = 0; t < 2; ++t)
                    acc[s][t] = __builtin_amdgcn_mfma_f32_16x16x32_bf16(af[s], bfr[t], acc[s][t], 0, 0, 0);
        }
        asm volatile("s_barrier" ::: "memory");
        if (i + 3 < nt) STAGEAB(i + 3, jb);
    }
#pragma unroll
    for (int s = 0; s < 2; ++s)
#pragma unroll
        for (int t = 0; t < 2; ++t)
#pragma unroll
            for (int rg = 0; rg < 4; ++rg) {
                int rl = wm + s * 16 + q * 4 + rg;
                if (rl < rows) {
                    int gc = n0 + wn + t * 16 + lm;
                    int tok = toks[rl];
                    out[(size_t)tok * E + gc] = scale[tok] * (acc[s][t][rg] + bias[gc]);
                }
            }
}

extern "C" void kernel_launch(void* const* d_in, const int* in_sizes, int n_in,
                              void* d_out, int out_size, void* d_ws, size_t ws_size,
                              hipStream_t stream) {
    const float* x        = (const float*)d_in[0];
    const float* gw1      = (const float*)d_in[1];
    const float* gb1      = (const float*)d_in[2];
    const float* gw2      = (const float*)d_in[3];
    const float* gb2      = (const float*)d_in[4];
    const float* ebias    = (const float*)d_in[5];
    const float* pm_alpha = (const float*)d_in[6];
    const float* dfc_w    = (const float*)d_in[7];
    const float* dfc_b    = (const float*)d_in[8];
    const float* dproj_w  = (const float*)d_in[9];
    const float* dproj_b  = (const float*)d_in[10];
    const float* sfc_w    = (const float*)d_in[11];
    const float* sfc_b    = (const float*)d_in[12];
    const float* sproj_w  = (const float*)d_in[13];
    const float* sproj_b  = (const float*)d_in[14];
    const float* p2_w     = (const float*)d_in[15];
    const float* p2_v     = (const float*)d_in[16];
    const float* p2_alpha = (const float*)d_in[17];
    const float* p2_b     = (const float*)d_in[18];
    const float* p2_bias  = (const float*)d_in[19];
    const float* p4_w     = (const float*)d_in[20];
    const float* p4_v     = (const float*)d_in[21];
    const float* p4_alpha = (const float*)d_in[22];
    const float* p4_b     = (const float*)d_in[23];
    const float* p4_bias  = (const float*)d_in[24];
    const float* rg_u     = (const float*)d_in[25];
    const float* rg_a     = (const float*)d_in[26];
    const float* rg_b     = (const float*)d_in[27];
    const float* rg_bias  = (const float*)d_in[28];
    const float* fl_dw    = (const float*)d_in[29];
    const float* fl_db    = (const float*)d_in[30];
    const float* fl_uw    = (const float*)d_in[31];
    const float* fl_ub    = (const float*)d_in[32];
    float* out = (float*)d_out;

    char* ws = (char*)d_ws;
    size_t off = 0;
    int*            counts = (int*)(ws + off);            off += 256;
    float*          scale  = (float*)(ws + off);          off += (size_t)NTOK * 4;
    int*            tlist  = (int*)(ws + off);            off += (size_t)NEXP * NTOK * 4;
    float*          cdot   = (float*)(ws + off);          off += (size_t)3 * NTOK * NCH * 4;
    unsigned short* Cm     = (unsigned short*)(ws + off); off += (size_t)NTOK * 64 * 2;
    unsigned short* bta    = (unsigned short*)(ws + off); off += (size_t)E * 64 * 2;
    unsigned short* btm    = (unsigned short*)(ws + off); off += (size_t)E * 64 * 2;
    unsigned short* w1cheap= (unsigned short*)(ws + off); off += (size_t)64 * 2048 * 2;
    unsigned short* w1cat  = (unsigned short*)(ws + off); off += (size_t)GH * 2048 * 2;
    unsigned short* dfc_wt = (unsigned short*)(ws + off); off += (size_t)2048 * 1024 * 2;
    unsigned short* dpj_wt = (unsigned short*)(ws + off); off += (size_t)1024 * 2048 * 2;
    unsigned short* sfc_wt = (unsigned short*)(ws + off); off += (size_t)1024 * 1024 * 2;
    unsigned short* spj_wt = (unsigned short*)(ws + off); off += (size_t)1024 * 1024 * 2;
    unsigned short* x_hi   = (unsigned short*)(ws + off); off += (size_t)NTOK * E * 2;
    // Union region: gate phase {x_lo} then expert phase {h1, h2}
    char* U = ws + off;
    unsigned short* x_lo = (unsigned short*)U;                              // 16 MB
    unsigned short* h1   = (unsigned short*)U;                              // 16 MB (2048 x 2048)
    unsigned short* h2   = (unsigned short*)(U + (size_t)16 * 1024 * 1024); // 8 MB (2048 x 1024)
    // 3 hp partials (3 x 8 MB = 24 MB) live in d_out (dead after finalize;
    // coefgemm then rewrites every token row, gemm2 overwrites e0/e1 rows).
    float* hp = out;

    hipMemsetAsync(counts, 0, 256, stream);
    prep_kernel<<<8516, 256, 0, stream>>>(x, x_hi, x_lo, gw1, w1cat,
                                          p2_w, p4_w, rg_u, fl_dw, w1cheap,
                                          p2_bias, p2_v, p4_bias, p4_v,
                                          rg_a, rg_bias, fl_uw, fl_ub, bta, btm,
                                          dfc_w, dfc_wt, dproj_w, dpj_wt,
                                          sfc_w, sfc_wt, sproj_w, spj_wt);
    gate_partial_kernel<<<384, 256, 0, stream>>>(
        x_hi, x_lo, w1cat, w1cheap, hp, cdot);
    gate_finalize_kernel<<<NTOK / 32, 256, 0, stream>>>(
        hp, gb1, gw2, gb2, ebias, pm_alpha, cdot,
        p2_alpha, p2_b, p4_alpha, p4_b, rg_b, fl_db,
        scale, counts, tlist, Cm);
    // blocks [0,2048): gemm1 (32 x 64-row tiles = 2048 rows per expert);
    // blocks [2048,4096): cheap coefficient-GEMM over all 8192 tokens.
    moe_gemm1_kernel<<<4096, 256, 0, stream>>>(
        x_hi, dfc_wt, sfc_wt, dfc_b, sfc_b, counts, tlist, h1, h2,
        Cm, bta, btm, x, scale, out);
    moe_gemm2_kernel<<<1024, 256, 0, stream>>>(
        h1, h2, dpj_wt, spj_wt, dproj_b, sproj_b, counts, tlist, scale, out);
    (void)in_sizes; (void)n_in; (void)out_size; (void)ws_size;
}